// Round 16
// baseline (966.032 us; speedup 1.0000x reference)
//
#include <hip/hip_runtime.h>
#include <hip/hip_bf16.h>

#define B_    16
#define R_    13
#define N_    392
#define F_    256
#define RN_   (R_*N_)        // 5096
#define M_    (B_*RN_)       // 81536
#define POOL_ 512
#define NCLS_ 200
#define KP_   416            // N padded to 13*32 for MFMA K

typedef __attribute__((ext_vector_type(4))) float f32x4;
typedef __attribute__((ext_vector_type(8))) short bf16x8;
typedef __attribute__((ext_vector_type(8))) unsigned short u16x8;

__device__ __forceinline__ unsigned short f2b(float f){
  union { float f; unsigned u; } v; v.f = f;
  unsigned r = v.u + 0x7FFF + ((v.u >> 16) & 1);   // RNE
  return (unsigned short)(r >> 16);
}
__device__ __forceinline__ float b2f(unsigned short b){
  union { unsigned u; float f; } v; v.u = ((unsigned)b) << 16;
  return v.f;
}

// ---------------- reduction helpers ----------------
__device__ __forceinline__ float warpMax(float v){
  #pragma unroll
  for (int o = 32; o; o >>= 1) v = fmaxf(v, __shfl_down(v, o));
  return v;
}
__device__ __forceinline__ float warpSum(float v){
  #pragma unroll
  for (int o = 32; o; o >>= 1) v += __shfl_down(v, o);
  return v;
}
__device__ __forceinline__ float blockMax(float v, float* red){
  v = warpMax(v);
  __syncthreads();
  if ((threadIdx.x & 63) == 0) red[threadIdx.x >> 6] = v;
  __syncthreads();
  return fmaxf(fmaxf(red[0], red[1]), fmaxf(red[2], red[3]));
}
__device__ __forceinline__ float blockSum(float v, float* red){
  v = warpSum(v);
  __syncthreads();
  if ((threadIdx.x & 63) == 0) red[threadIdx.x >> 6] = v;
  __syncthreads();
  return red[0] + red[1] + red[2] + red[3];
}
__device__ __forceinline__ float eluf(float v){
  return v > 0.f ? v : (expf(v) - 1.f);
}

// ---------------- weight transpose+convert: W[K,N] fp32 -> Wt[N,K] bf16 ----------------
__global__ __launch_bounds__(256) void cvt_wt(const float* __restrict__ W,
    unsigned short* __restrict__ Wt, int K, int N){
  const int id = blockIdx.x*256 + threadIdx.x;
  if (id < K*N){
    const int n = id / K, k = id - n*K;
    Wt[id] = f2b(W[k*N + n]);
  }
}

// ---------------- x fp32 -> bf16 (identity layout), 8 elems/thread ----------------
__global__ __launch_bounds__(256) void cvt_x(const float* __restrict__ x,
    unsigned short* __restrict__ xb){
  const long t = (long)blockIdx.x*256 + threadIdx.x;
  const float4 a = *(const float4*)&x[t*8];
  const float4 b = *(const float4*)&x[t*8 + 4];
  u16x8 o = {f2b(a.x),f2b(a.y),f2b(a.z),f2b(a.w),f2b(b.x),f2b(b.y),f2b(b.z),f2b(b.w)};
  *(u16x8*)&xb[t*8] = o;
}

// ---------------- x fp32 -> bf16 transposed view: row (b*N+n)*R+r <- phys (b*R+r)*N+n ----
__global__ __launch_bounds__(256) void cvt_xT(const float* __restrict__ x,
    unsigned short* __restrict__ xb){
  const long t = (long)blockIdx.x*256 + threadIdx.x;  // one 8-col chunk
  const int l  = (int)(t >> 5);
  const int c8 = ((int)t & 31) * 8;
  const int b  = l / RN_;
  const int rem = l - b*RN_;
  const int n  = rem / R_;
  const int r  = rem - n*R_;
  const long prow = (long)(b*R_ + r)*N_ + n;
  const float4 a  = *(const float4*)&x[prow*F_ + c8];
  const float4 bb = *(const float4*)&x[prow*F_ + c8 + 4];
  u16x8 o = {f2b(a.x),f2b(a.y),f2b(a.z),f2b(a.w),f2b(bb.x),f2b(bb.y),f2b(bb.z),f2b(bb.w)};
  *(u16x8*)&xb[(long)l*F_ + c8] = o;
}

// ---------------- MFMA GEMM: out[M,256] = A[M,256]bf16 @ Wt[256,256]^T bf16 ----------------
template<int ACT>
__global__ __launch_bounds__(256) void mfma_gemm(
    const unsigned short* __restrict__ A, const unsigned short* __restrict__ Wt,
    const float* __restrict__ bias, unsigned short* __restrict__ out){
  __shared__ unsigned short A_lds[128][72];
  __shared__ unsigned short W_lds[64][72];
  const int tid = threadIdx.x;
  const int lane = tid & 63, wid = tid >> 6;
  const int wr = wid >> 1, wc = wid & 1;
  const int lr = lane & 15, lk = lane >> 4;
  const int row0 = blockIdx.x * 128;
  const int col0 = blockIdx.y * 64;

  f32x4 acc[4][2] = {};
  for (int k0 = 0; k0 < 256; k0 += 64){
    #pragma unroll
    for (int i = 0; i < 4; ++i){
      const int chunk = tid + i*256;
      const int r = chunk >> 3, c8 = (chunk & 7)*8;
      *(u16x8*)&A_lds[r][c8] = *(const u16x8*)&A[(long)(row0 + r)*F_ + k0 + c8];
    }
    #pragma unroll
    for (int i = 0; i < 2; ++i){
      const int chunk = tid + i*256;
      const int r = chunk >> 3, c8 = (chunk & 7)*8;
      *(u16x8*)&W_lds[r][c8] = *(const u16x8*)&Wt[(long)(col0 + r)*F_ + k0 + c8];
    }
    __syncthreads();
    #pragma unroll
    for (int kk = 0; kk < 64; kk += 32){
      bf16x8 af[4], bf[2];
      #pragma unroll
      for (int m = 0; m < 4; ++m)
        af[m] = *(const bf16x8*)&A_lds[wr*64 + m*16 + lr][kk + lk*8];
      #pragma unroll
      for (int n = 0; n < 2; ++n)
        bf[n] = *(const bf16x8*)&W_lds[wc*32 + n*16 + lr][kk + lk*8];
      #pragma unroll
      for (int m = 0; m < 4; ++m)
        #pragma unroll
        for (int n = 0; n < 2; ++n)
          acc[m][n] = __builtin_amdgcn_mfma_f32_16x16x32_bf16(af[m], bf[n], acc[m][n], 0, 0, 0);
    }
    __syncthreads();
  }
  #pragma unroll
  for (int m = 0; m < 4; ++m){
    const int gr = row0 + wr*64 + m*16 + lk*4;
    #pragma unroll
    for (int n = 0; n < 2; ++n){
      const int gc = col0 + wc*32 + n*16 + lr;
      #pragma unroll
      for (int q = 0; q < 4; ++q){
        float v = acc[m][n][q];
        if (ACT) v = 1.f/(1.f + expf(-(v + bias[gc])));
        out[(long)(gr + q)*F_ + gc] = f2b(v);
      }
    }
  }
}

// ---------------- xk [g][392][256] -> xkT [g][256][416] bf16 (zero-padded K) ----------------
__global__ __launch_bounds__(256) void xkT_k(const unsigned short* __restrict__ xk,
    unsigned short* __restrict__ xkT){
  __shared__ unsigned short tile[32][36];
  const int n0 = blockIdx.x * 32;      // 0..12 -> covers 416
  const int f0 = blockIdx.y * 32;
  const int g  = blockIdx.z;
  const int t  = threadIdx.x;
  {
    const int nl = t >> 3, fl = (t & 7)*4;
    ushort4 v = {0,0,0,0};
    const int n = n0 + nl;
    if (n < N_) v = *(const ushort4*)&xk[((long)g*N_ + n)*F_ + f0 + fl];
    tile[nl][fl] = v.x; tile[nl][fl+1] = v.y; tile[nl][fl+2] = v.z; tile[nl][fl+3] = v.w;
  }
  __syncthreads();
  {
    const int fl = t >> 3, nl = (t & 7)*4;
    ushort4 o = {tile[nl][fl], tile[nl+1][fl], tile[nl+2][fl], tile[nl+3][fl]};
    *(ushort4*)&xkT[((long)g*F_ + f0 + fl)*KP_ + n0 + nl] = o;
  }
}

// ---------------- per-graph column sum (APPNP), direct store ----------------
__global__ __launch_bounds__(256) void colsum_k(const unsigned short* __restrict__ h1,
    float* __restrict__ S, int nn){
  const int g = blockIdx.x;
  const int f = threadIdx.x;
  const unsigned short* base = h1 + (long)g*nn*F_ + f;
  float s = 0.f;
  for (int n = 0; n < nn; ++n) s += b2f(base[(long)n*F_]);
  S[(long)g*F_ + f] = s;
}

// ---------------- h = 0.5*(S+h1)/(nn+1) + 0.5*h1 + x  (bf16 out) ----------------
template<int XMODE>
__global__ __launch_bounds__(256) void combine_k(const unsigned short* __restrict__ h1,
    const float* __restrict__ S, const float* __restrict__ x,
    unsigned short* __restrict__ hb){
  const long t = (long)blockIdx.x*256 + threadIdx.x;   // 4-elem groups
  const long row = t >> 6;
  const int f4 = ((int)t & 63) * 4;
  int g, xrow;
  if (XMODE == 0){ g = (int)(row / N_); xrow = (int)row; }
  else {
    g = (int)(row / R_);
    const int b   = (int)(row / RN_);
    const int rem = (int)(row - (long)b*RN_);
    const int n   = rem / R_;
    const int r   = rem - n*R_;
    xrow = (b*R_ + r)*N_ + n;
  }
  const float inv = (XMODE == 0) ? (1.f/(N_+1)) : (1.f/(R_+1));
  const ushort4 hraw = *(const ushort4*)&h1[row*F_ + f4];
  const float4 h1v = {b2f(hraw.x), b2f(hraw.y), b2f(hraw.z), b2f(hraw.w)};
  const float4 Sv  = *(const float4*)&S[(long)g*F_ + f4];
  const float4 xv  = *(const float4*)&x[(long)xrow*F_ + f4];
  float4 o;
  o.x = 0.5f*(Sv.x + h1v.x)*inv + 0.5f*h1v.x + xv.x;
  o.y = 0.5f*(Sv.y + h1v.y)*inv + 0.5f*h1v.y + xv.y;
  o.z = 0.5f*(Sv.z + h1v.z)*inv + 0.5f*h1v.z + xv.z;
  o.w = 0.5f*(Sv.w + h1v.w)*inv + 0.5f*h1v.w + xv.w;
  const ushort4 ob = {f2b(o.x), f2b(o.y), f2b(o.z), f2b(o.w)};
  *(ushort4*)&hb[row*F_ + f4] = ob;
}

// ---------------- per-node attention scalars s,t (bf16 xk) ----------------
__global__ __launch_bounds__(256) void st_k(const unsigned short* __restrict__ xk,
    const float* __restrict__ a_self, const float* __restrict__ a_neigh,
    float* __restrict__ sv, float* __restrict__ tv){
  const int lane = threadIdx.x & 63;
  const int wid  = threadIdx.x >> 6;
  const long row = (long)blockIdx.x*4 + wid;
  const ushort4 raw = *(const ushort4*)&xk[row*F_ + lane*4];
  const float4 v  = {b2f(raw.x), b2f(raw.y), b2f(raw.z), b2f(raw.w)};
  const float4 as = *(const float4*)&a_self[lane*4];
  const float4 an = *(const float4*)&a_neigh[lane*4];
  float s = v.x*as.x + v.y*as.y + v.z*as.z + v.w*as.w;
  float t = v.x*an.x + v.y*an.y + v.z*an.z + v.w*an.w;
  #pragma unroll
  for (int o = 32; o; o >>= 1){ s += __shfl_down(s, o); t += __shfl_down(t, o); }
  if (lane == 0){ sv[row] = s; tv[row] = t; }
}

// ---------------- intra-ROI attention (MFMA, P in registers) ----------------
// grid (7, 208); block 256 = 4 waves. Wave wid owns output rows m0+wid*16..+15,
// ALL 256 cols. Lane (lr,lk) computes its own A-fragment values
// P[lr][ks*32+lk*8+j] = exp(lrelu(s[lr]+t[col]) - zm[lr])  (unnormalized, <=1),
// held in 13 bf16x8 regs. Row-normalization deferred to epilogue via invr
// (rowsum = local sum + shfl_xor(16,32) across the 4 lanes sharing lr).
// No Wp LDS -> ~2 KB LDS, occupancy VGPR-capped instead of LDS-capped.
__global__ __launch_bounds__(256) void attn_intra_k(
    const unsigned short* __restrict__ xkT, const float* __restrict__ sv,
    const float* __restrict__ tv, const float* __restrict__ bg,
    unsigned short* __restrict__ hx2){
  __shared__ float t_lds[N_];
  __shared__ float s_lds[64];
  __shared__ float invr[4][16];
  __shared__ float red[4];
  const int g  = blockIdx.y;
  const int m0 = blockIdx.x * 64;
  const int tid = threadIdx.x;
  const int lane = tid & 63, wid = tid >> 6;
  const int lr = lane & 15, lk = lane >> 4;

  for (int n = tid; n < N_; n += 256) t_lds[n] = tv[(long)g*N_ + n];
  if (tid < 64) s_lds[tid] = (m0 + tid < N_) ? sv[(long)g*N_ + m0 + tid] : 0.f;
  __syncthreads();
  float tl = -1e30f;
  for (int n = tid; n < N_; n += 256) tl = fmaxf(tl, t_lds[n]);
  const float tmax = blockMax(tl, red);

  // ---- P fragments in registers (all lanes parallel; no serial row loop) ----
  const float srow = s_lds[wid*16 + lr];
  float zm = srow + tmax; zm = zm > 0.f ? zm : 0.2f*zm;   // lrelu monotone -> row max
  float lsum = 0.f;
  bf16x8 pfrag[13];
  #pragma unroll
  for (int ks = 0; ks < 13; ++ks){
    const int base = ks*32 + lk*8;
    u16x8 pk;
    #pragma unroll
    for (int j = 0; j < 8; ++j){
      const int col = base + j;
      float e = 0.f;
      if (col < N_){
        float z = srow + t_lds[col];
        z = z > 0.f ? z : 0.2f*z;
        e = expf(z - zm);
        lsum += e;
      }
      pk[j] = f2b(e);
    }
    pfrag[ks] = *(bf16x8*)&pk;
  }
  lsum += __shfl_xor(lsum, 16);
  lsum += __shfl_xor(lsum, 32);        // full row sum on all 4 lanes sharing lr
  if (lk == 0) invr[wid][lr] = 1.f / lsum;
  __syncthreads();

  // ---- MFMA: wave covers all 256 cols; B-frags streamed from global ----
  const unsigned short* xkTg = xkT + (long)g*F_*KP_;
  f32x4 acc[16] = {};
  for (int ks = 0; ks < 13; ++ks){
    const int k0 = ks*32 + lk*8;
    #pragma unroll
    for (int ni = 0; ni < 16; ++ni){
      const bf16x8 bfr = *(const bf16x8*)&xkTg[(long)(ni*16 + lr)*KP_ + k0];
      acc[ni] = __builtin_amdgcn_mfma_f32_16x16x32_bf16(pfrag[ks], bfr, acc[ni], 0, 0, 0);
    }
  }

  // ---- epilogue: normalize, bias, elu, + residual (in place) ----
  #pragma unroll
  for (int q = 0; q < 4; ++q){
    const int lm = lk*4 + q;
    const int m = m0 + wid*16 + lm;
    if (m < N_){
      const float iv = invr[wid][lm];
      #pragma unroll
      for (int ni = 0; ni < 16; ++ni){
        const int f = ni*16 + lr;
        const long idx = ((long)g*N_ + m)*F_ + f;
        const float v = eluf(acc[ni][q]*iv + bg[f]) + b2f(hx2[idx]);
        hx2[idx] = f2b(v);
      }
    }
  }
}

// ---------------- inter-ROI attention (graphs of 13), in-place residual ----------------
__global__ __launch_bounds__(256) void attn_inter_k(
    const unsigned short* __restrict__ xk, const float* __restrict__ sv,
    const float* __restrict__ tv, const float* __restrict__ bg,
    unsigned short* __restrict__ hx2){
  const int g = blockIdx.x;
  const int tid = threadIdx.x;
  __shared__ float w_lds[R_][R_];
  __shared__ float invr[R_];
  __shared__ float st[R_], tt[R_];
  if (tid < R_){ st[tid] = sv[(long)g*R_ + tid]; tt[tid] = tv[(long)g*R_ + tid]; }
  __syncthreads();
  if (tid < R_){
    const float sm = st[tid];
    float z[R_];
    float zm = -1e30f;
    #pragma unroll
    for (int n = 0; n < R_; ++n){
      float zz = sm + tt[n];
      zz = zz > 0.f ? zz : 0.2f*zz;
      z[n] = zz;
      zm = fmaxf(zm, zz);
    }
    float sum = 0.f;
    #pragma unroll
    for (int n = 0; n < R_; ++n){
      const float e = expf(z[n] - zm);
      w_lds[tid][n] = e;
      sum += e;
    }
    invr[tid] = 1.f/sum;
  }
  __syncthreads();
  float acc[R_] = {};
  const unsigned short* xkg = xk + (long)g*R_*F_;
  #pragma unroll
  for (int n = 0; n < R_; ++n){
    const float xv = b2f(xkg[n*F_ + tid]);
    #pragma unroll
    for (int m = 0; m < R_; ++m) acc[m] += w_lds[m][n]*xv;
  }
  const float bgv = bg[tid];
  #pragma unroll
  for (int m = 0; m < R_; ++m){
    const long idx = ((long)g*R_ + m)*F_ + tid;
    const float hv = b2f(hx2[idx]);
    hx2[idx] = f2b(eluf(acc[m]*invr[m] + bgv) + hv);
  }
}

// ---------------- pooling: dual MFMA GEMM + sigmoid-gate + j-reduce ----------------
__global__ __launch_bounds__(256) void pool_mfma(
    const unsigned short* __restrict__ x2, const unsigned short* __restrict__ wat,
    const unsigned short* __restrict__ wft, const float* __restrict__ ba,
    const float* __restrict__ bfp, float* __restrict__ pooled){
  __shared__ unsigned short A_lds[128][72];
  __shared__ unsigned short Wa_lds[64][72];
  __shared__ unsigned short Wf_lds[64][72];
  __shared__ float redp[8][64];
  const int tid = threadIdx.x;
  const int lane = tid & 63, wid = tid >> 6;
  const int wr = wid >> 1, wc = wid & 1;
  const int lr = lane & 15, lk = lane >> 4;
  const int j0 = blockIdx.x * 128;
  const int c0 = blockIdx.y * 64;
  const int b  = blockIdx.z;
  const unsigned short* xb = x2 + (long)b * RN_ * F_;

  f32x4 accA[4][2] = {}, accF[4][2] = {};
  for (int k0 = 0; k0 < 256; k0 += 64){
    #pragma unroll
    for (int i = 0; i < 4; ++i){
      const int chunk = tid + i*256;
      const int r = chunk >> 3, c8 = (chunk & 7)*8;
      u16x8 v = {};
      if (j0 + r < RN_) v = *(const u16x8*)&xb[(long)(j0 + r)*F_ + k0 + c8];
      *(u16x8*)&A_lds[r][c8] = v;
    }
    #pragma unroll
    for (int i = 0; i < 2; ++i){
      const int chunk = tid + i*256;
      const int r = chunk >> 3, c8 = (chunk & 7)*8;
      *(u16x8*)&Wa_lds[r][c8] = *(const u16x8*)&wat[(long)(c0 + r)*F_ + k0 + c8];
      *(u16x8*)&Wf_lds[r][c8] = *(const u16x8*)&wft[(long)(c0 + r)*F_ + k0 + c8];
    }
    __syncthreads();
    #pragma unroll
    for (int kk = 0; kk < 64; kk += 32){
      bf16x8 af[4], bfa[2], bff[2];
      #pragma unroll
      for (int m = 0; m < 4; ++m)
        af[m] = *(const bf16x8*)&A_lds[wr*64 + m*16 + lr][kk + lk*8];
      #pragma unroll
      for (int n = 0; n < 2; ++n){
        bfa[n] = *(const bf16x8*)&Wa_lds[wc*32 + n*16 + lr][kk + lk*8];
        bff[n] = *(const bf16x8*)&Wf_lds[wc*32 + n*16 + lr][kk + lk*8];
      }
      #pragma unroll
      for (int m = 0; m < 4; ++m)
        #pragma unroll
        for (int n = 0; n < 2; ++n){
          accA[m][n] = __builtin_amdgcn_mfma_f32_16x16x32_bf16(af[m], bfa[n], accA[m][n], 0, 0, 0);
          accF[m][n] = __builtin_amdgcn_mfma_f32_16x16x32_bf16(af[m], bff[n], accF[m][n], 0, 0, 0);
        }
    }
    __syncthreads();
  }
  float csum[2] = {0.f, 0.f};
  #pragma unroll
  for (int m = 0; m < 4; ++m){
    const int jb = wr*64 + m*16 + lk*4;
    #pragma unroll
    for (int q = 0; q < 4; ++q){
      if (j0 + jb + q < RN_){
        #pragma unroll
        for (int n = 0; n < 2; ++n){
          const int c = c0 + wc*32 + n*16 + lr;
          const float a = accA[m][n][q] + ba[c];
          const float f = accF[m][n][q] + bfp[c];
          csum[n] += f / (1.f + expf(-a));
        }
      }
    }
  }
  #pragma unroll
  for (int n = 0; n < 2; ++n) redp[wr*4 + lk][wc*32 + n*16 + lr] = csum[n];
  __syncthreads();
  if (tid < 64){
    float s = 0.f;
    #pragma unroll
    for (int i = 0; i < 8; ++i) s += redp[i][tid];
    atomicAdd(&pooled[(long)b*POOL_ + c0 + tid], s);
  }
}

// ---------------- BN + classifier + softmax ----------------
__global__ __launch_bounds__(256) void final_k(const float* __restrict__ pooled,
    const float* __restrict__ gamma, const float* __restrict__ beta,
    const float* __restrict__ mean, const float* __restrict__ var,
    const float* __restrict__ wout, const float* __restrict__ bout,
    float* __restrict__ out){
  const int b = blockIdx.x, tid = threadIdx.x;
  __shared__ float bn[POOL_];
  __shared__ float red[4];
  for (int c = tid; c < POOL_; c += 256){
    const float p = pooled[(long)b*POOL_ + c];
    bn[c] = (p - mean[c]) * rsqrtf(var[c] + 1e-3f) * gamma[c] + beta[c];
  }
  __syncthreads();
  float logit = -3.0e38f;
  if (tid < NCLS_){
    float s = bout[tid];
    for (int k = 0; k < POOL_; ++k) s += bn[k]*wout[k*NCLS_ + tid];
    logit = s;
  }
  const float mx = blockMax(logit, red);
  float e = (tid < NCLS_) ? expf(logit - mx) : 0.f;
  const float tot = blockSum(e, red);
  if (tid < NCLS_) out[(long)b*NCLS_ + tid] = e / tot;
}

// ---------------- launcher ----------------
extern "C" void kernel_launch(void* const* d_in, const int* in_sizes, int n_in,
                              void* d_out, int out_size, void* d_ws, size_t ws_size,
                              hipStream_t stream){
  const float* x       = (const float*)d_in[0];
  const float* w_mlp   = (const float*)d_in[1];
  const float* b_mlp   = (const float*)d_in[2];
  const float* k_gat   = (const float*)d_in[3];
  const float* a_self  = (const float*)d_in[4];
  const float* a_neigh = (const float*)d_in[5];
  const float* b_gat   = (const float*)d_in[6];
  const float* wf_pool = (const float*)d_in[7];
  const float* bf_pool = (const float*)d_in[8];
  const float* wa_pool = (const float*)d_in[9];
  const float* ba_pool = (const float*)d_in[10];
  const float* bn_g    = (const float*)d_in[11];
  const float* bn_b    = (const float*)d_in[12];
  const float* bn_m    = (const float*)d_in[13];
  const float* bn_v    = (const float*)d_in[14];
  const float* w_out   = (const float*)d_in[15];
  const float* b_out   = (const float*)d_in[16];
  float* out = (float*)d_out;

  // Workspace (135.7 MB):
  //   abuf bf16 [M,F]: h1 then xk
  //   xbuf bf16 [M,F]: x_bf -> h_bf -> x2 (attn residual+write IN PLACE)
  //   xkT  bf16 [B*R][256][416]: transposed xk for attention B-operand (intra only)
  //   weights bf16, Sbuf fp32 [B*N,F], s/t [M], pooled [B,512]
  char* p = (char*)d_ws;
  const long MF = (long)M_ * F_;
  unsigned short* abuf = (unsigned short*)p;  p += MF*2;
  unsigned short* xbuf = (unsigned short*)p;  p += MF*2;
  unsigned short* xkT  = (unsigned short*)p;  p += (long)B_*R_*F_*KP_*2;
  unsigned short* wmt  = (unsigned short*)p;  p += 65536*2;
  unsigned short* kgt  = (unsigned short*)p;  p += 65536*2;
  unsigned short* wat  = (unsigned short*)p;  p += 131072*2;
  unsigned short* wft  = (unsigned short*)p;  p += 131072*2;
  float*          Sbuf = (float*)p;           p += (long)B_*N_*F_*4;
  float*          sbuf = (float*)p;           p += (long)M_*4;
  float*          tbuf = (float*)p;           p += (long)M_*4;
  float*          pooled = (float*)p;         p += (long)B_*POOL_*4;

  hipMemsetAsync(pooled, 0, (size_t)B_*POOL_*sizeof(float), stream);

  cvt_wt<<<256, 256, 0, stream>>>(w_mlp,   wmt, 256, 256);
  cvt_wt<<<256, 256, 0, stream>>>(k_gat,   kgt, 256, 256);
  cvt_wt<<<512, 256, 0, stream>>>(wa_pool, wat, 256, 512);
  cvt_wt<<<512, 256, 0, stream>>>(wf_pool, wft, 256, 512);

  const dim3 ggrid(M_/128, F_/64);                  // (637, 4)
  const dim3 pgrid((RN_+127)/128, POOL_/64, B_);    // (40, 8, 16)

  // ---- intra path ----
  cvt_x<<<M_*F_/2048, 256, 0, stream>>>(x, xbuf);
  mfma_gemm<1><<<ggrid, 256, 0, stream>>>(xbuf, wmt, b_mlp, abuf);            // h1
  colsum_k<<<B_*R_, 256, 0, stream>>>(abuf, Sbuf, N_);
  combine_k<0><<<M_*64/256, 256, 0, stream>>>(abuf, Sbuf, x, xbuf);           // h_bf (in xbuf)
  mfma_gemm<0><<<ggrid, 256, 0, stream>>>(xbuf, kgt, nullptr, abuf);          // xk
  xkT_k<<<dim3(KP_/32, F_/32, B_*R_), 256, 0, stream>>>(abuf, xkT);
  st_k<<<M_/4, 256, 0, stream>>>(abuf, a_self, a_neigh, sbuf, tbuf);
  attn_intra_k<<<dim3(7, B_*R_), 256, 0, stream>>>(xkT, sbuf, tbuf, b_gat, xbuf);
  pool_mfma<<<pgrid, 256, 0, stream>>>(xbuf, wat, wft, ba_pool, bf_pool, pooled);

  // ---- inter path ----
  cvt_xT<<<M_*F_/2048, 256, 0, stream>>>(x, xbuf);
  mfma_gemm<1><<<ggrid, 256, 0, stream>>>(xbuf, wmt, b_mlp, abuf);            // h1 (transposed view)
  colsum_k<<<B_*N_, 256, 0, stream>>>(abuf, Sbuf, R_);
  combine_k<1><<<M_*64/256, 256, 0, stream>>>(abuf, Sbuf, x, xbuf);           // h2_bf
  mfma_gemm<0><<<ggrid, 256, 0, stream>>>(xbuf, kgt, nullptr, abuf);          // xk
  st_k<<<M_/4, 256, 0, stream>>>(abuf, a_self, a_neigh, sbuf, tbuf);
  attn_inter_k<<<B_*N_, 256, 0, stream>>>(abuf, sbuf, tbuf, b_gat, xbuf);
  pool_mfma<<<pgrid, 256, 0, stream>>>(xbuf, wat, wft, ba_pool, bf_pool, pooled);

  // ---- classifier ----
  final_k<<<B_, 256, 0, stream>>>(pooled, bn_g, bn_b, bn_m, bn_v, w_out, b_out, out);
}